// Round 8
// baseline (417.097 us; speedup 1.0000x reference)
//
#include <hip/hip_runtime.h>

// LightGCN 3-layer propagation, pull-based CSR, bf16 ego intermediates.
// Round 8: gather goes 8 nodes/wave (one per 8-lane group, no shuffles,
// pipelined pairs prefetch) — r7's 1 node/wave ran only ~2 loop iters then
// paid 24 shfl + idle epilogue (latency-bound, 150K waves). Build: hist
// saves per-(tile,bucket) counts so scatter skips its re-histogram pass.

#define NUM_USERS 100000
#define NUM_ITEMS 50000
#define EMB_DIM   64
#define N_EDGES   2000000
#define N_NODES   (NUM_USERS + NUM_ITEMS)          // 150000
#define NODE_FLOATS (N_NODES * EMB_DIM)            // 9,600,000
#define NODE_F4     (NODE_FLOATS / 4)              // 2,400,000

#define NBUCKET  512
#define NPB      293        // nodes per bucket; 512*293 = 150016 >= 150000
#define NPART    8          // reservation partitions (XCD heuristic)
#define NCNT     (NBUCKET * NPART)                  // 4096
#define BT       512        // threads in bucket passes
#define VPT      8          // edges per thread in bucket passes
#define TILE     (BT * VPT)                         // 4096
#define NTILE    ((N_EDGES + TILE - 1) / TILE)      // 489

typedef unsigned int uint;
typedef unsigned short ushort;
typedef unsigned long long u64;

__device__ __forceinline__ uint pack2_bf16(float a, float b) {
    uint ua = __float_as_uint(a), ub = __float_as_uint(b);
    ua += 0x7FFFu + ((ua >> 16) & 1u);      // RNE
    ub += 0x7FFFu + ((ub >> 16) & 1u);
    return (ua >> 16) | (ub & 0xFFFF0000u);
}
__device__ __forceinline__ float bflo(uint u) { return __uint_as_float(u << 16); }
__device__ __forceinline__ float bfhi(uint u) { return __uint_as_float(u & 0xFFFF0000u); }

// ---------- init: egoA(bf16) = concat(user,item) ----------
__global__ void lgcn_init(const float4* __restrict__ user,
                          const float4* __restrict__ item,
                          uint2* __restrict__ egoA) {
    const int n_user4 = NUM_USERS * EMB_DIM / 4;
    for (int i = blockIdx.x * blockDim.x + threadIdx.x; i < NODE_F4;
         i += gridDim.x * blockDim.x) {
        float4 v = (i < n_user4) ? user[i] : item[i - n_user4];
        egoA[i] = make_uint2(pack2_bf16(v.x, v.y), pack2_bf16(v.z, v.w));
    }
}

__global__ void zero_ints(int* __restrict__ p, int n) {
    int i = blockIdx.x * blockDim.x + threadIdx.x;
    if (i < n) p[i] = 0;
}

// ---------- pass A: histogram; saves per-tile counts for pass B ----------
__global__ __launch_bounds__(BT) void bucket_hist(const int* __restrict__ src,
                                                  int* __restrict__ bucketCount,
                                                  int* __restrict__ tileCnt) {
    __shared__ int cnt[NBUCKET];
    int t = threadIdx.x;
    int part = blockIdx.x & (NPART - 1);
    cnt[t] = 0;
    __syncthreads();
    int base = blockIdx.x * TILE + t;
    #pragma unroll
    for (int k = 0; k < VPT; ++k) {
        int e = base + k * BT;
        if (e < N_EDGES) atomicAdd(&cnt[src[e] / NPB], 1);
    }
    __syncthreads();
    int c = cnt[t];
    tileCnt[blockIdx.x * NBUCKET + t] = c;
    if (c) atomicAdd(&bucketCount[t * NPART + part], c);
}

// ---------- scan over 4096 (bucket,part) counters (1 block, 1024 thr) ----------
__global__ __launch_bounds__(1024) void bucket_scan(const int* __restrict__ bucketCount,
                                                    int* __restrict__ bucketOffset,
                                                    int* __restrict__ gCur,
                                                    int* __restrict__ rowPtr) {
    __shared__ int s[1024];
    int t = threadIdx.x;
    int4 c = *(const int4*)(bucketCount + t * 4);
    int sum = c.x + c.y + c.z + c.w;
    s[t] = sum;
    __syncthreads();
    for (int off = 1; off < 1024; off <<= 1) {
        int x = (t >= off) ? s[t - off] : 0;
        __syncthreads();
        s[t] += x;
        __syncthreads();
    }
    int base = s[t] - sum;   // exclusive
    int i0 = t * 4;
    bucketOffset[i0]     = base;
    bucketOffset[i0 + 1] = base + c.x;
    bucketOffset[i0 + 2] = base + c.x + c.y;
    bucketOffset[i0 + 3] = base + c.x + c.y + c.z;
    gCur[i0]     = base;
    gCur[i0 + 1] = base + c.x;
    gCur[i0 + 2] = base + c.x + c.y;
    gCur[i0 + 3] = base + c.x + c.y + c.z;
    if (t == 0) {
        bucketOffset[NCNT] = N_EDGES;
        rowPtr[N_NODES] = N_EDGES;
    }
}

// ---------- pass B: scatter packed edges into (bucket,part) runs ----------
// packed u64: [norm:32][src_local:9][dst:18]
__global__ __launch_bounds__(BT) void bucket_scatter(const int* __restrict__ src,
                                                     const int* __restrict__ dst,
                                                     const float* __restrict__ norm,
                                                     const int* __restrict__ tileCnt,
                                                     int* __restrict__ gCur,
                                                     u64* __restrict__ bpair) {
    __shared__ int cnt[NBUCKET];
    __shared__ int bbase[NBUCKET];
    int t = threadIdx.x;
    int part = blockIdx.x & (NPART - 1);
    int c = tileCnt[blockIdx.x * NBUCKET + t];
    bbase[t] = c ? atomicAdd(&gCur[t * NPART + part], c) : 0;
    cnt[t] = 0;
    __syncthreads();
    int base = blockIdx.x * TILE + t;
    #pragma unroll
    for (int k = 0; k < VPT; ++k) {
        int e = base + k * BT;
        if (e < N_EDGES) {
            int s = src[e];
            int b = s / NPB;
            int sl = s - b * NPB;                    // 0..292
            int r = atomicAdd(&cnt[b], 1);
            uint lo = (uint)dst[e] | ((uint)sl << 18);
            bpair[bbase[b] + r] = (u64)lo | ((u64)(uint)__float_as_uint(norm[e]) << 32);
        }
    }
}

// ---------- pass C: per-bucket CSR finalize (counting sort by src_local) ----------
__global__ __launch_bounds__(1024) void csr_finalize(const int* __restrict__ bucketOffset,
                                                     const u64* __restrict__ bpair,
                                                     int* __restrict__ rowPtr,
                                                     u64* __restrict__ pairs) {
    __shared__ int cnt[NBUCKET];
    __shared__ int cur[NBUCKET];
    int b = blockIdx.x;
    int t = threadIdx.x;          // 1024 threads
    int beg = bucketOffset[b * NPART];
    int end = bucketOffset[b * NPART + NPART];
    int nodeBase = b * NPB;

    if (t < NBUCKET) cnt[t] = 0;
    __syncthreads();
    for (int i = beg + t; i < end; i += 1024) {
        uint lo = (uint)bpair[i];
        atomicAdd(&cnt[(lo >> 18) & 0x1FF], 1);
    }
    __syncthreads();
    int v = (t < NBUCKET) ? cnt[t] : 0;
    for (int off = 1; off < NBUCKET; off <<= 1) {     // inclusive scan, 512-wide
        int x = (t >= off && t < NBUCKET) ? cnt[t - off] : 0;
        __syncthreads();
        if (t < NBUCKET) cnt[t] += x;
        __syncthreads();
    }
    if (t < NBUCKET) {
        int excl = cnt[t] - v;
        cur[t] = excl;
        int node = nodeBase + t;
        if (t < NPB && node < N_NODES) rowPtr[node] = beg + excl;
    }
    __syncthreads();
    for (int i = beg + t; i < end; i += 1024) {
        u64 p = bpair[i];
        int s = ((uint)p >> 18) & 0x1FF;
        int r = atomicAdd(&cur[s], 1);
        pairs[beg + r] = p;
    }
}

// ---------- gather: 8 nodes/wave (one per 8-lane group), no shuffles ----------
__global__ __launch_bounds__(256) void lgcn_gather(const ushort* __restrict__ ego,
                                                   ushort* __restrict__ nego,
                                                   float* __restrict__ acc,
                                                   const ushort* __restrict__ ego0,
                                                   const int* __restrict__ rowPtr,
                                                   const u64* __restrict__ pairs,
                                                   float scale, int writeEgo,
                                                   int accFromEgo0) {
    int wave = threadIdx.x >> 6;
    int lane = threadIdx.x & 63;
    int g    = lane >> 3;           // group = which node
    int sub  = lane & 7;            // 8 bf16 dims per lane
    int node = blockIdx.x * 32 + wave * 8 + g;
    bool valid = node < N_NODES;
    int beg = valid ? rowPtr[node]     : 0;
    int end = valid ? rowPtr[node + 1] : 0;

    float s0 = 0.f, s1 = 0.f, s2 = 0.f, s3 = 0.f;
    float s4 = 0.f, s5 = 0.f, s6 = 0.f, s7 = 0.f;

    int i = beg;
    u64 p = (i < end) ? __builtin_nontemporal_load(&pairs[i]) : 0;
    while (i < end) {
        int inext = i + 1;
        u64 pn = (inext < end) ? __builtin_nontemporal_load(&pairs[inext]) : 0;
        uint lo = (uint)p;
        float w = __uint_as_float((uint)(p >> 32));
        int d = lo & 0x3FFFF;
        uint4 r = *(const uint4*)(ego + ((size_t)d << 6) + (sub << 3));
        s0 += w * bflo(r.x);  s1 += w * bfhi(r.x);
        s2 += w * bflo(r.y);  s3 += w * bfhi(r.y);
        s4 += w * bflo(r.z);  s5 += w * bfhi(r.z);
        s6 += w * bflo(r.w);  s7 += w * bfhi(r.w);
        p = pn;
        i = inext;
    }

    if (valid) {
        size_t ro = ((size_t)node << 6) + (sub << 3);   // dims sub*8..sub*8+7
        float4* ap = (float4*)(acc + ro);
        float4 a0, a1;
        if (accFromEgo0) {
            uint4 z = *(const uint4*)(ego0 + ro);
            a0 = make_float4(bflo(z.x), bfhi(z.x), bflo(z.y), bfhi(z.y));
            a1 = make_float4(bflo(z.z), bfhi(z.z), bflo(z.w), bfhi(z.w));
        } else {
            a0 = ap[0];
            a1 = ap[1];
        }
        a0.x = (a0.x + s0) * scale;
        a0.y = (a0.y + s1) * scale;
        a0.z = (a0.z + s2) * scale;
        a0.w = (a0.w + s3) * scale;
        a1.x = (a1.x + s4) * scale;
        a1.y = (a1.y + s5) * scale;
        a1.z = (a1.z + s6) * scale;
        a1.w = (a1.w + s7) * scale;
        ap[0] = a0;
        ap[1] = a1;
        if (writeEgo) {
            uint4* np = (uint4*)(nego + ro);
            *np = make_uint4(pack2_bf16(s0, s1), pack2_bf16(s2, s3),
                             pack2_bf16(s4, s5), pack2_bf16(s6, s7));
        }
    }
}

extern "C" void kernel_launch(void* const* d_in, const int* in_sizes, int n_in,
                              void* d_out, int out_size, void* d_ws, size_t ws_size,
                              hipStream_t stream) {
    const float* user_emb  = (const float*)d_in[0];
    const float* item_emb  = (const float*)d_in[1];
    const float* edge_norm = (const float*)d_in[2];
    const int*   edge_src  = (const int*)d_in[3];
    const int*   edge_dst  = (const int*)d_in[4];
    float* acc = (float*)d_out;

    char* w = (char*)d_ws;
    ushort* egoA  = (ushort*)w;                      w += (size_t)NODE_FLOATS * 2;   // 19.2 MB
    ushort* egoB  = (ushort*)w;                      w += (size_t)NODE_FLOATS * 2;   // 19.2 MB
    u64*   pairs  = (u64*)w;                         w += (size_t)N_EDGES * 8;       // 16 MB
    u64*   bpair  = (u64*)w;                         w += (size_t)N_EDGES * 8;       // 16 MB
    int*   tileCnt = (int*)w;                        w += (size_t)NTILE * NBUCKET * 4; // ~1 MB
    int*   rowPtr = (int*)w;                         w += (size_t)(N_NODES + 4) * 4;
    int*   bucketCount  = (int*)w;                   w += (size_t)NCNT * 4;
    int*   bucketOffset = (int*)w;                   w += (size_t)(NCNT + 4) * 4;
    int*   gCur   = (int*)w;

    const int T = 256;
    const int EW_BLOCKS = 2048;
    const int GATHER_BLOCKS = (N_NODES + 31) / 32;   // 4688, 32 nodes/block

    lgcn_init<<<EW_BLOCKS, T, 0, stream>>>(
        (const float4*)user_emb, (const float4*)item_emb, (uint2*)egoA);

    zero_ints<<<NCNT / T, T, 0, stream>>>(bucketCount, NCNT);
    bucket_hist<<<NTILE, BT, 0, stream>>>(edge_src, bucketCount, tileCnt);
    bucket_scan<<<1, 1024, 0, stream>>>(bucketCount, bucketOffset, gCur, rowPtr);
    bucket_scatter<<<NTILE, BT, 0, stream>>>(edge_src, edge_dst, edge_norm,
                                             tileCnt, gCur, bpair);
    csr_finalize<<<NBUCKET, 1024, 0, stream>>>(bucketOffset, bpair,
                                               rowPtr, pairs);

    // Layer 1: A -> B, acc = ego0 + B
    lgcn_gather<<<GATHER_BLOCKS, T, 0, stream>>>(egoA, egoB, acc, egoA,
                                                 rowPtr, pairs, 1.0f, 1, 1);
    // Layer 2: B -> A, acc += A
    lgcn_gather<<<GATHER_BLOCKS, T, 0, stream>>>(egoB, egoA, acc, egoA,
                                                 rowPtr, pairs, 1.0f, 1, 0);
    // Layer 3: A -> (none), acc = (acc + ego3) * 0.25
    lgcn_gather<<<GATHER_BLOCKS, T, 0, stream>>>(egoA, egoB, acc, egoA,
                                                 rowPtr, pairs, 0.25f, 0, 0);
}